// Round 3
// baseline (910.996 us; speedup 1.0000x reference)
//
#include <hip/hip_runtime.h>

#define BN 2
#define CH 256
#define HH 96
#define WW 96
#define NL 4
#define HW (HH*WW)        // 9216
#define KK (CH*9)         // 2304
#define NPOS (BN*HW)      // 18432

#define MPOS 32           // positions per block
#define NBLK (NPOS/MPOS)  // 576
#define CKCH 64           // channels per K-chunk
#define CKLEN (CKCH*9)    // 576
#define NCK 4
#define SAMW 584          // bf16 row stride: 1168 B = 73 x 16B (odd block stride)

#define NOCHK 16          // off-conv channel chunks
#define OCCH (CH/NOCHK)

#define WB_PER_L (288*256*8)   // bf16 per layer, layout [k/8][oc][k%8]
#define WB_TOT (NL*WB_PER_L)
#define OWT_PER_L (KK*20)
#define OWT_TOT (NL*OWT_PER_L)

typedef __attribute__((ext_vector_type(8))) short short8;
typedef __attribute__((ext_vector_type(4))) float f32x4;

__device__ __forceinline__ unsigned short f2bf(float f) {
    union { float f; unsigned int u; } v; v.f = f;
    unsigned int r = v.u + 0x7fffu + ((v.u >> 16) & 1u);
    return (unsigned short)(r >> 16);
}

// Pack dw -> wB (bf16, B-fragment order) and off_w -> owT (f32, [c*9+k][oc pad 20])
__global__ void prep_kernel(const float* __restrict__ dw, const float* __restrict__ off_w,
                            unsigned short* __restrict__ wB, float* __restrict__ owT) {
    int idx = blockIdx.x * 256 + threadIdx.x;
    if (idx < WB_TOT) {
        int j  = idx & 7;
        int oc = (idx >> 3) & 255;
        int g  = (idx >> 11) % 288;
        int l  = idx / WB_PER_L;
        int k  = g * 8 + j;
        int c  = k / 9, t9 = k - 9 * c;
        wB[idx] = f2bf(dw[((size_t)(l * CH + oc) * CH + c) * 9 + t9]);
    } else {
        int i2 = idx - WB_TOT;
        if (i2 >= OWT_TOT) return;
        int ocp = i2 % 20;
        int r   = (i2 / 20) % KK;
        int l   = i2 / OWT_PER_L;
        int c   = r / 9, t9 = r - 9 * c;
        owT[i2] = (ocp < 18) ? off_w[((size_t)(l * 18 + ocp) * CH + c) * 9 + t9] : 0.f;
    }
}

// Offset conv, partial over 16-channel chunk. grid = 72 pos-blocks * 16 chunks.
__global__ void __launch_bounds__(256)
off_conv2_kernel(const float* __restrict__ x, const float* __restrict__ owT,
                 float* __restrict__ part) {
    __shared__ __align__(16) float wch[OCCH * 180];
    const int pb = blockIdx.x >> 4;
    const int cc = blockIdx.x & 15;
    const int tid = threadIdx.x;
    for (int i = tid; i < OCCH * 180; i += 256)
        wch[i] = owT[(size_t)(cc * OCCH) * 180 + i];

    const int pos = pb * 256 + tid;
    const int b = pos / HW, rem = pos - b * HW;
    const int h = rem / WW, w = rem - h * WW;
    int offk[9]; float mk[9];
    #pragma unroll
    for (int k = 0; k < 9; ++k) {
        int dy = k / 3 - 1, dx = k % 3 - 1;
        int yk = h + dy, xk = w + dx;
        bool valid = ((unsigned)yk < HH) && ((unsigned)xk < WW);
        offk[k] = min(max(yk, 0), HH - 1) * WW + min(max(xk, 0), WW - 1);
        mk[k] = valid ? 1.f : 0.f;
    }
    float acc[20];
    #pragma unroll
    for (int o = 0; o < 20; ++o) acc[o] = 0.f;
    __syncthreads();

    const float* xc = x + (size_t)(b * CH + cc * OCCH) * HW;
    for (int c = 0; c < OCCH; ++c, xc += HW) {
        float xv[9];
        #pragma unroll
        for (int k = 0; k < 9; ++k) xv[k] = xc[offk[k]] * mk[k];
        const float4* wr = (const float4*)&wch[c * 180];
        #pragma unroll
        for (int k = 0; k < 9; ++k) {
            #pragma unroll
            for (int o4 = 0; o4 < 5; ++o4) {
                float4 wv4 = wr[k * 5 + o4];
                acc[o4*4+0] = fmaf(xv[k], wv4.x, acc[o4*4+0]);
                acc[o4*4+1] = fmaf(xv[k], wv4.y, acc[o4*4+1]);
                acc[o4*4+2] = fmaf(xv[k], wv4.z, acc[o4*4+2]);
                acc[o4*4+3] = fmaf(xv[k], wv4.w, acc[o4*4+3]);
            }
        }
    }
    float* pp = part + (size_t)(cc * BN + b) * 18 * HW + rem;
    #pragma unroll
    for (int o = 0; o < 18; ++o) pp[(size_t)o * HW] = acc[o];
}

// Fused bilinear sampling + bf16 MFMA GEMM. Block = 32 positions x 256 oc.
// Tap table hoisted to registers (per position+tap: 2 row bases, 4 weights).
__global__ void __launch_bounds__(256, 3)
deform_mfma_kernel(const float* __restrict__ x, const float* __restrict__ part,
                   const float* __restrict__ ob, const unsigned short* __restrict__ wB,
                   const float* __restrict__ db, float* __restrict__ out) {
    __shared__ __align__(16) unsigned short sam[MPOS * SAMW];   // 37376 B, reused as cT
    __shared__ float offs[MPOS][18];
    const int tid = threadIdx.x;
    int blk = (int)blockIdx.x;
    blk = (blk & 7) * (NBLK / 8) + (blk >> 3);   // XCD swizzle: contiguous band per XCD
    const int pos0 = blk * MPOS;
    const int b0   = pos0 / HW;
    const int rem0 = pos0 - b0 * HW;
    const int h0   = rem0 / WW;
    const int w0   = rem0 - h0 * WW;             // w0 % 32 == 0

    // offsets: sum 16 partial chunks + bias
    for (int i = tid; i < MPOS * 18; i += 256) {
        int p = i / 18, oc = i - 18 * p;
        float s = ob[oc];
        #pragma unroll
        for (int cc = 0; cc < NOCHK; ++cc)
            s += part[((size_t)(cc * BN + b0) * 18 + oc) * HW + rem0 + p];
        offs[p][oc] = s;
    }
    __syncthreads();

    const int p_s = tid & 31;        // sampling position
    const int kq  = tid >> 5;        // 0..7: channel-subgroup
    const int m   = tid & 15;
    const int q   = (tid >> 4) & 3;
    const int wv  = tid >> 6;

    // ---- per-thread tap table (9 taps for position p_s) ----
    int   ti0[9], ti1[9];
    float tw0[9], tw1[9], tw2[9], tw3[9];
    #pragma unroll
    for (int t9 = 0; t9 < 9; ++t9) {
        int ky = t9 / 3, kx = t9 - 3 * (t9 / 3);
        float py = (float)(h0 - 1 + ky) + offs[p_s][2 * t9];
        float px = (float)(w0 + p_s - 1 + kx) + offs[p_s][2 * t9 + 1];
        float yf = floorf(py), xf = floorf(px);
        int y0 = (int)yf, x0 = (int)xf;
        float wy1 = py - yf, wx1 = px - xf;
        float fy0 = ((unsigned)y0       < HH) ? 1.f - wy1 : 0.f;
        float fy1 = ((unsigned)(y0 + 1) < HH) ? wy1       : 0.f;
        float fx0 = ((unsigned)x0       < WW) ? 1.f - wx1 : 0.f;
        float fx1 = ((unsigned)(x0 + 1) < WW) ? wx1       : 0.f;
        int y0c = min(max(y0, 0), HH - 1), y1c = min(max(y0 + 1, 0), HH - 1);
        int x0c = min(max(x0, 0), WW - 1), x1c = min(max(x0 + 1, 0), WW - 1);
        int bx  = min(max(x0, 0), WW - 2);       // float2 window [bx, bx+1]
        float wA = (x0c == bx     ? fx0 : 0.f) + (x1c == bx     ? fx1 : 0.f);
        float wBv= (x0c == bx + 1 ? fx0 : 0.f) + (x1c == bx + 1 ? fx1 : 0.f);
        ti0[t9] = y0c * WW + bx;
        ti1[t9] = y1c * WW + bx;
        tw0[t9] = fy0 * wA; tw1[t9] = fy0 * wBv;
        tw2[t9] = fy1 * wA; tw3[t9] = fy1 * wBv;
    }

    f32x4 acc[2][4] = {};
    const float* xb = x + (size_t)b0 * CH * HW;

    for (int ck = 0; ck < NCK; ++ck) {
        __syncthreads();
        // ---- sampling: 8 channels x 9 taps per thread, b128-packed LDS writes ----
        const float* xc = xb + (size_t)(ck * CKCH + kq * 8) * HW;
        unsigned short* srow = sam + p_s * SAMW + kq * 72;
        uint4 ub;
        unsigned int cur = 0;
        #pragma unroll
        for (int ci = 0; ci < 8; ++ci) {
            const float* xcc = xc + (size_t)ci * HW;
            #pragma unroll
            for (int t9 = 0; t9 < 9; ++t9) {
                float2 l0, l1;
                __builtin_memcpy(&l0, xcc + ti0[t9], 8);
                __builtin_memcpy(&l1, xcc + ti1[t9], 8);
                float v = l0.x * tw0[t9] + l0.y * tw1[t9]
                        + l1.x * tw2[t9] + l1.y * tw3[t9];
                unsigned int hv = f2bf(v);
                const int s = ci * 9 + t9;
                if ((s & 1) == 0) cur = hv;
                else {
                    unsigned int full = cur | (hv << 16);
                    const int wsel = (s >> 1) & 3;
                    if (wsel == 0) ub.x = full;
                    else if (wsel == 1) ub.y = full;
                    else if (wsel == 2) ub.z = full;
                    else ub.w = full;
                    if ((s & 7) == 7) *(uint4*)(srow + (s - 7)) = ub;
                }
            }
        }
        __syncthreads();
        // ---- GEMM on this chunk: 18 k-tiles of 32, 2 m-tiles ----
        const unsigned short* wpg = wB + (size_t)(ck * 72 + q) * (256 * 8);
        const unsigned short* arow0 = sam + m * SAMW + q * 8;
        const unsigned short* arow1 = arow0 + 16 * SAMW;
        for (int kb = 0; kb < 18; ++kb) {
            short8 av0 = *(const short8*)(arow0 + kb * 32);
            short8 av1 = *(const short8*)(arow1 + kb * 32);
            const unsigned short* wkb = wpg + (size_t)kb * (4 * 256 * 8)
                                       + (size_t)(wv * 64 + m) * 8;
            #pragma unroll
            for (int t = 0; t < 4; ++t) {
                short8 bv = *(const short8*)(wkb + t * 16 * 8);
                acc[0][t] = __builtin_amdgcn_mfma_f32_16x16x32_bf16(av0, bv, acc[0][t], 0, 0, 0);
                acc[1][t] = __builtin_amdgcn_mfma_f32_16x16x32_bf16(av1, bv, acc[1][t], 0, 0, 0);
            }
        }
    }

    // ---- epilogue: LDS transpose, coalesced stores ----
    __syncthreads();
    float* cT = (float*)sam;   // [256][33] f32 = 33792 B <= 37376
    #pragma unroll
    for (int mt = 0; mt < 2; ++mt)
        #pragma unroll
        for (int t = 0; t < 4; ++t) {
            int oc = wv * 64 + t * 16 + m;
            #pragma unroll
            for (int r = 0; r < 4; ++r)
                cT[oc * 33 + mt * 16 + q * 4 + r] = acc[mt][t][r];
        }
    __syncthreads();
    const int p_o = tid & 31;
    const int og  = tid >> 5;
    float* op = out + ((size_t)b0 * CH) * HW + rem0 + p_o;
    #pragma unroll 4
    for (int i = 0; i < 32; ++i) {
        int oc = og * 32 + i;
        op[(size_t)oc * HW] = fmaxf(cT[oc * 33 + p_o] + db[oc], 0.f);
    }
}

extern "C" void kernel_launch(void* const* d_in, const int* in_sizes, int n_in,
                              void* d_out, int out_size, void* d_ws, size_t ws_size,
                              hipStream_t stream) {
    const float* x     = (const float*)d_in[0];
    const float* off_w = (const float*)d_in[1];
    const float* off_b = (const float*)d_in[2];
    const float* dw    = (const float*)d_in[3];
    const float* db    = (const float*)d_in[4];

    float* ws   = (float*)d_ws;
    float* part = ws;                                        // 16*BN*18*HW
    float* buf0 = part + (size_t)NOCHK * BN * 18 * HW;       // BN*CH*HW
    float* buf1 = buf0 + (size_t)BN * CH * HW;               // BN*CH*HW
    float* owT  = buf1 + (size_t)BN * CH * HW;               // OWT_TOT
    unsigned short* wB = (unsigned short*)(owT + OWT_TOT);   // WB_TOT bf16

    prep_kernel<<<(WB_TOT + OWT_TOT + 255) / 256, 256, 0, stream>>>(dw, off_w, wB, owT);

    const float* cur = x;
    for (int l = 0; l < NL; ++l) {
        float* nxt = (l == NL - 1) ? (float*)d_out : ((l & 1) ? buf1 : buf0);
        off_conv2_kernel<<<72 * NOCHK, 256, 0, stream>>>(
            cur, owT + (size_t)l * OWT_PER_L, part);
        deform_mfma_kernel<<<NBLK, 256, 0, stream>>>(
            cur, part, off_b + l * 18, wB + (size_t)l * WB_PER_L, db + l * CH, nxt);
        cur = nxt;
    }
}

// Round 5
// 839.379 us; speedup vs baseline: 1.0853x; 1.0853x over previous
//
#include <hip/hip_runtime.h>

#define BN 2
#define CH 256
#define HH 96
#define WW 96
#define NL 4
#define HW (HH*WW)        // 9216
#define KK (CH*9)         // 2304
#define NPOS (BN*HW)      // 18432

#define MPOS 32           // positions per block
#define NBLK (NPOS/MPOS)  // 576
#define CKCH 64           // channels per K-chunk
#define CKLEN (CKCH*9)    // 576
#define NCK 4
#define SAMW 584          // bf16 row stride: 1168 B = 73 x 16B (odd block stride)

#define NOCHK 16          // off-conv channel chunks
#define OCCH (CH/NOCHK)

#define WB_PER_L (288*256*8)   // bf16 per layer, layout [k/8][oc][k%8], k in permuted col order
#define WB_TOT (NL*WB_PER_L)
#define OWT_PER_L (KK*20)
#define OWT_TOT (NL*OWT_PER_L)

typedef __attribute__((ext_vector_type(8))) short short8;
typedef __attribute__((ext_vector_type(4))) float f32x4;

__device__ __forceinline__ unsigned short f2bf(float f) {
    union { float f; unsigned int u; } v; v.f = f;
    unsigned int r = v.u + 0x7fffu + ((v.u >> 16) & 1u);
    return (unsigned short)(r >> 16);
}

// Pack dw -> wB (bf16, B-fragment order over PERMUTED k columns) and
// off_w -> owT (f32, [c*9+k][oc pad 20]).
// Permuted column: col = ck*576 + kq*72 + t9*8 + ci, channel c = ck*64+kq*8+ci.
__global__ void prep_kernel(const float* __restrict__ dw, const float* __restrict__ off_w,
                            unsigned short* __restrict__ wB, float* __restrict__ owT) {
    int idx = blockIdx.x * 256 + threadIdx.x;
    if (idx < WB_TOT) {
        int j  = idx & 7;
        int oc = (idx >> 3) & 255;
        int g  = (idx >> 11) % 288;
        int l  = idx / WB_PER_L;
        int col = g * 8 + j;
        int ck = col / CKLEN;
        int r  = col - ck * CKLEN;
        int kq = r / 72;
        int rr = r - 72 * kq;
        int t9 = rr >> 3;
        int ci = rr & 7;
        int c  = ck * CKCH + kq * 8 + ci;
        wB[idx] = f2bf(dw[((size_t)(l * CH + oc) * CH + c) * 9 + t9]);
    } else {
        int i2 = idx - WB_TOT;
        if (i2 >= OWT_TOT) return;
        int ocp = i2 % 20;
        int r   = (i2 / 20) % KK;
        int l   = i2 / OWT_PER_L;
        int c   = r / 9, t9 = r - 9 * c;
        owT[i2] = (ocp < 18) ? off_w[((size_t)(l * 18 + ocp) * CH + c) * 9 + t9] : 0.f;
    }
}

// Offset conv, partial over 16-channel chunk. grid = 72 pos-blocks * 16 chunks.
__global__ void __launch_bounds__(256)
off_conv2_kernel(const float* __restrict__ x, const float* __restrict__ owT,
                 float* __restrict__ part) {
    __shared__ __align__(16) float wch[OCCH * 180];
    const int pb = blockIdx.x >> 4;
    const int cc = blockIdx.x & 15;
    const int tid = threadIdx.x;
    for (int i = tid; i < OCCH * 180; i += 256)
        wch[i] = owT[(size_t)(cc * OCCH) * 180 + i];

    const int pos = pb * 256 + tid;
    const int b = pos / HW, rem = pos - b * HW;
    const int h = rem / WW, w = rem - h * WW;
    int offk[9]; float mk[9];
    #pragma unroll
    for (int k = 0; k < 9; ++k) {
        int dy = k / 3 - 1, dx = k % 3 - 1;
        int yk = h + dy, xk = w + dx;
        bool valid = ((unsigned)yk < HH) && ((unsigned)xk < WW);
        offk[k] = min(max(yk, 0), HH - 1) * WW + min(max(xk, 0), WW - 1);
        mk[k] = valid ? 1.f : 0.f;
    }
    float acc[20];
    #pragma unroll
    for (int o = 0; o < 20; ++o) acc[o] = 0.f;
    __syncthreads();

    const float* xc = x + (size_t)(b * CH + cc * OCCH) * HW;
    for (int c = 0; c < OCCH; ++c, xc += HW) {
        float xv[9];
        #pragma unroll
        for (int k = 0; k < 9; ++k) xv[k] = xc[offk[k]] * mk[k];
        const float4* wr = (const float4*)&wch[c * 180];
        #pragma unroll
        for (int k = 0; k < 9; ++k) {
            #pragma unroll
            for (int o4 = 0; o4 < 5; ++o4) {
                float4 wv4 = wr[k * 5 + o4];
                acc[o4*4+0] = fmaf(xv[k], wv4.x, acc[o4*4+0]);
                acc[o4*4+1] = fmaf(xv[k], wv4.y, acc[o4*4+1]);
                acc[o4*4+2] = fmaf(xv[k], wv4.z, acc[o4*4+2]);
                acc[o4*4+3] = fmaf(xv[k], wv4.w, acc[o4*4+3]);
            }
        }
    }
    float* pp = part + (size_t)(cc * BN + b) * 18 * HW + rem;
    #pragma unroll
    for (int o = 0; o < 18; ++o) pp[(size_t)o * HW] = acc[o];
}

// Fused bilinear sampling + bf16 MFMA GEMM. Block = 32 positions x 256 oc.
// Tap table in LDS (computed once); sampling loops tap-outer/channel-inner
// over permuted k columns so LDS writes stay b128-packed.
__global__ void __launch_bounds__(256)
deform_mfma_kernel(const float* __restrict__ x, const float* __restrict__ part,
                   const float* __restrict__ ob, const unsigned short* __restrict__ wB,
                   const float* __restrict__ db, float* __restrict__ out) {
    __shared__ __align__(16) unsigned short sam[MPOS * SAMW];   // 37376 B, reused as cT
    __shared__ float offs[MPOS][18];
    __shared__ __align__(16) float taps[MPOS * 9 * 8];          // 9216 B
    const int tid = threadIdx.x;
    int blk = (int)blockIdx.x;
    blk = (blk & 7) * (NBLK / 8) + (blk >> 3);   // XCD swizzle: contiguous band per XCD
    const int pos0 = blk * MPOS;
    const int b0   = pos0 / HW;
    const int rem0 = pos0 - b0 * HW;
    const int h0   = rem0 / WW;
    const int w0   = rem0 - h0 * WW;             // w0 % 32 == 0, all 32 pos share (b0,h0)

    // offsets: sum 16 partial chunks + bias
    for (int i = tid; i < MPOS * 18; i += 256) {
        int p = i / 18, oc = i - 18 * p;
        float s = ob[oc];
        #pragma unroll
        for (int cc = 0; cc < NOCHK; ++cc)
            s += part[((size_t)(cc * BN + b0) * 18 + oc) * HW + rem0 + p];
        offs[p][oc] = s;
    }
    __syncthreads();

    // ---- tap table: strided over all 288 (position, tap) records ----
    for (int rec = tid; rec < MPOS * 9; rec += 256) {
        int p  = rec / 9, t9 = rec - 9 * p;
        int ky = t9 / 3, kx = t9 - 3 * (t9 / 3);
        float py = (float)(h0 - 1 + ky) + offs[p][2 * t9];
        float px = (float)(w0 + p - 1 + kx) + offs[p][2 * t9 + 1];
        float yf = floorf(py), xf = floorf(px);
        int y0 = (int)yf, x0 = (int)xf;
        float wy1 = py - yf, wx1 = px - xf;
        float fy0 = ((unsigned)y0       < HH) ? 1.f - wy1 : 0.f;
        float fy1 = ((unsigned)(y0 + 1) < HH) ? wy1       : 0.f;
        float fx0 = ((unsigned)x0       < WW) ? 1.f - wx1 : 0.f;
        float fx1 = ((unsigned)(x0 + 1) < WW) ? wx1       : 0.f;
        int y0c = min(max(y0, 0), HH - 1), y1c = min(max(y0 + 1, 0), HH - 1);
        int x0c = min(max(x0, 0), WW - 1), x1c = min(max(x0 + 1, 0), WW - 1);
        int bx  = min(max(x0, 0), WW - 2);       // float2 window [bx, bx+1]
        float wA  = (x0c == bx     ? fx0 : 0.f) + (x1c == bx     ? fx1 : 0.f);
        float wBv = (x0c == bx + 1 ? fx0 : 0.f) + (x1c == bx + 1 ? fx1 : 0.f);
        float* tv = taps + rec * 8;
        tv[0] = __int_as_float(y0c * WW + bx);
        tv[1] = __int_as_float(y1c * WW + bx);
        tv[2] = fy0 * wA;  tv[3] = fy0 * wBv;
        tv[4] = fy1 * wA;  tv[5] = fy1 * wBv;
    }

    const int p_s = tid & 31;        // sampling position
    const int kq  = tid >> 5;        // 0..7: 8-channel subgroup
    const int m   = tid & 15;
    const int q   = (tid >> 4) & 3;
    const int wv  = tid >> 6;

    f32x4 acc[2][4] = {};
    const float* xb = x + (size_t)b0 * CH * HW;

    for (int ck = 0; ck < NCK; ++ck) {
        __syncthreads();
        // ---- sampling: tap-outer, 8-channels-inner; one b128 LDS write per tap ----
        const float* xc0 = xb + (size_t)(ck * CKCH + kq * 8) * HW;
        unsigned short* srow = sam + p_s * SAMW + kq * 72;
        const float* tp = taps + (p_s * 9) * 8;
        #pragma unroll
        for (int t9 = 0; t9 < 9; ++t9) {
            const float* tv = tp + t9 * 8;
            int   i0  = __float_as_int(tv[0]);
            int   i1  = __float_as_int(tv[1]);
            float u0 = tv[2], u1 = tv[3], u2 = tv[4], u3 = tv[5];
            unsigned int pk[4];
            #pragma unroll
            for (int ci = 0; ci < 8; ++ci) {
                const float* xcc = xc0 + (size_t)ci * HW;
                float2 l0, l1;
                __builtin_memcpy(&l0, xcc + i0, 8);
                __builtin_memcpy(&l1, xcc + i1, 8);
                float v = l0.x * u0 + l0.y * u1 + l1.x * u2 + l1.y * u3;
                unsigned int hv = f2bf(v);
                if (ci & 1) pk[ci >> 1] |= hv << 16;
                else        pk[ci >> 1]  = hv;
            }
            uint4 ub; ub.x = pk[0]; ub.y = pk[1]; ub.z = pk[2]; ub.w = pk[3];
            *(uint4*)(srow + t9 * 8) = ub;
        }
        __syncthreads();
        // ---- GEMM on this chunk: 18 k-tiles of 32, 2 m-tiles ----
        const unsigned short* wpg = wB + (size_t)(ck * 72 + q) * (256 * 8);
        const unsigned short* arow0 = sam + m * SAMW + q * 8;
        const unsigned short* arow1 = arow0 + 16 * SAMW;
        for (int kb = 0; kb < 18; ++kb) {
            short8 av0 = *(const short8*)(arow0 + kb * 32);
            short8 av1 = *(const short8*)(arow1 + kb * 32);
            const unsigned short* wkb = wpg + (size_t)kb * (4 * 256 * 8)
                                       + (size_t)(wv * 64 + m) * 8;
            #pragma unroll
            for (int t = 0; t < 4; ++t) {
                short8 bv = *(const short8*)(wkb + t * 16 * 8);
                acc[0][t] = __builtin_amdgcn_mfma_f32_16x16x32_bf16(av0, bv, acc[0][t], 0, 0, 0);
                acc[1][t] = __builtin_amdgcn_mfma_f32_16x16x32_bf16(av1, bv, acc[1][t], 0, 0, 0);
            }
        }
    }

    // ---- epilogue: LDS transpose, coalesced stores ----
    __syncthreads();
    float* cT = (float*)sam;   // [256][33] f32 = 33792 B <= 37376
    #pragma unroll
    for (int mt = 0; mt < 2; ++mt)
        #pragma unroll
        for (int t = 0; t < 4; ++t) {
            int oc = wv * 64 + t * 16 + m;
            #pragma unroll
            for (int r = 0; r < 4; ++r)
                cT[oc * 33 + mt * 16 + q * 4 + r] = acc[mt][t][r];
        }
    __syncthreads();
    const int p_o = tid & 31;
    const int og  = tid >> 5;
    float* op = out + ((size_t)b0 * CH) * HW + rem0 + p_o;
    #pragma unroll 4
    for (int i = 0; i < 32; ++i) {
        int oc = og * 32 + i;
        op[(size_t)oc * HW] = fmaxf(cT[oc * 33 + p_o] + db[oc], 0.f);
    }
}

extern "C" void kernel_launch(void* const* d_in, const int* in_sizes, int n_in,
                              void* d_out, int out_size, void* d_ws, size_t ws_size,
                              hipStream_t stream) {
    const float* x     = (const float*)d_in[0];
    const float* off_w = (const float*)d_in[1];
    const float* off_b = (const float*)d_in[2];
    const float* dw    = (const float*)d_in[3];
    const float* db    = (const float*)d_in[4];

    float* ws   = (float*)d_ws;
    float* part = ws;                                        // 16*BN*18*HW
    float* buf0 = part + (size_t)NOCHK * BN * 18 * HW;       // BN*CH*HW
    float* buf1 = buf0 + (size_t)BN * CH * HW;               // BN*CH*HW
    float* owT  = buf1 + (size_t)BN * CH * HW;               // OWT_TOT
    unsigned short* wB = (unsigned short*)(owT + OWT_TOT);   // WB_TOT bf16

    prep_kernel<<<(WB_TOT + OWT_TOT + 255) / 256, 256, 0, stream>>>(dw, off_w, wB, owT);

    const float* cur = x;
    for (int l = 0; l < NL; ++l) {
        float* nxt = (l == NL - 1) ? (float*)d_out : ((l & 1) ? buf1 : buf0);
        off_conv2_kernel<<<72 * NOCHK, 256, 0, stream>>>(
            cur, owT + (size_t)l * OWT_PER_L, part);
        deform_mfma_kernel<<<NBLK, 256, 0, stream>>>(
            cur, part, off_b + l * 18, wB + (size_t)l * WB_PER_L, db + l * CH, nxt);
        cur = nxt;
    }
}

// Round 6
// 583.376 us; speedup vs baseline: 1.5616x; 1.4388x over previous
//
#include <hip/hip_runtime.h>

#define BN 2
#define CH 256
#define HH 96
#define WW 96
#define NL 4
#define HW (HH*WW)        // 9216
#define KK (CH*9)         // 2304
#define NPOS (BN*HW)      // 18432

#define MPOS 32           // positions per block
#define NBLK (NPOS/MPOS)  // 576
#define CKCH 64           // channels per K-chunk
#define CKLEN (CKCH*9)    // 576
#define NCK 4
#define SAMW 584          // bf16 row stride: 1168 B = 73 x 16B

#define NOCHK 8           // off-conv channel chunks
#define OCCH (CH/NOCHK)   // 32

#define WB_PER_L (288*256*8)   // bf16/layer, [k/8][oc][k%8], permuted cols (tap-major)
#define WB_TOT (NL*WB_PER_L)
#define OWT_PER_L (KK*20)
#define OWT_TOT (NL*OWT_PER_L)

typedef __attribute__((ext_vector_type(8))) short short8;
typedef __attribute__((ext_vector_type(4))) float f32x4;

__device__ __forceinline__ unsigned short f2bf(float f) {
    union { float f; unsigned int u; } v; v.f = f;
    unsigned int r = v.u + 0x7fffu + ((v.u >> 16) & 1u);
    return (unsigned short)(r >> 16);
}
__device__ __forceinline__ float bf2f(unsigned short h) {
    return __uint_as_float((unsigned int)h << 16);
}

// Pack dw -> wB (bf16, B-frag order over PERMUTED cols) and off_w -> owT.
// Permuted column: col = ck*576 + t9*64 + ci, channel c = ck*64 + ci.
__global__ void prep_kernel(const float* __restrict__ dw, const float* __restrict__ off_w,
                            unsigned short* __restrict__ wB, float* __restrict__ owT) {
    int idx = blockIdx.x * 256 + threadIdx.x;
    if (idx < WB_TOT) {
        int j  = idx & 7;
        int oc = (idx >> 3) & 255;
        int g  = (idx >> 11) % 288;
        int l  = idx / WB_PER_L;
        int col = g * 8 + j;
        int ck = col / CKLEN;
        int r  = col - ck * CKLEN;
        int t9 = r >> 6;
        int ci = r & 63;
        int c  = ck * CKCH + ci;
        wB[idx] = f2bf(dw[((size_t)(l * CH + oc) * CH + c) * 9 + t9]);
    } else {
        int i2 = idx - WB_TOT;
        if (i2 >= OWT_TOT) return;
        int ocp = i2 % 20;
        int r   = (i2 / 20) % KK;
        int l   = i2 / OWT_PER_L;
        int c   = r / 9, t9 = r - 9 * c;
        owT[i2] = (ocp < 18) ? off_w[((size_t)(l * 18 + ocp) * CH + c) * 9 + t9] : 0.f;
    }
}

// NCHW f32 -> channel-last bf16: xT[b][hw][c]. 64x64 LDS tile transpose.
__global__ void __launch_bounds__(256)
transpose_kernel(const float* __restrict__ src, unsigned short* __restrict__ xT) {
    __shared__ float tile[64][65];
    int blk = blockIdx.x;
    int b = blk / 576, r = blk - 576 * b;
    int hw0 = (r >> 2) * 64, c0 = (r & 3) * 64;
    int tid = threadIdx.x;
    int lane = tid & 63, grp = tid >> 6;
    const float* sp = src + (size_t)(b * CH + c0) * HW + hw0;
    #pragma unroll
    for (int i = 0; i < 16; ++i) {
        int c = grp * 16 + i;
        tile[c][lane] = sp[(size_t)c * HW + lane];
    }
    __syncthreads();
    unsigned short* dp = xT + (size_t)(b * HW + hw0) * CH + c0;
    #pragma unroll
    for (int i = 0; i < 16; ++i) {
        int hw = grp * 16 + i;
        dp[(size_t)hw * CH + lane] = f2bf(tile[lane][hw]);
    }
}

// Offset conv, partial over 32-channel chunk. grid = 72 pos-blocks * 8 chunks.
__global__ void __launch_bounds__(256)
off_conv2_kernel(const float* __restrict__ x, const float* __restrict__ owT,
                 float* __restrict__ part) {
    __shared__ __align__(16) float wch[OCCH * 180];   // 23040 B
    const int pb = blockIdx.x >> 3;
    const int cc = blockIdx.x & 7;
    const int tid = threadIdx.x;
    for (int i = tid; i < OCCH * 180; i += 256)
        wch[i] = owT[(size_t)(cc * OCCH) * 180 + i];

    const int pos = pb * 256 + tid;
    const int b = pos / HW, rem = pos - b * HW;
    const int h = rem / WW, w = rem - h * WW;
    int offk[9]; float mk[9];
    #pragma unroll
    for (int k = 0; k < 9; ++k) {
        int dy = k / 3 - 1, dx = k % 3 - 1;
        int yk = h + dy, xk = w + dx;
        bool valid = ((unsigned)yk < HH) && ((unsigned)xk < WW);
        offk[k] = min(max(yk, 0), HH - 1) * WW + min(max(xk, 0), WW - 1);
        mk[k] = valid ? 1.f : 0.f;
    }
    float acc[20];
    #pragma unroll
    for (int o = 0; o < 20; ++o) acc[o] = 0.f;
    __syncthreads();

    const float* xc = x + (size_t)(b * CH + cc * OCCH) * HW;
    for (int c = 0; c < OCCH; ++c, xc += HW) {
        float xv[9];
        #pragma unroll
        for (int k = 0; k < 9; ++k) xv[k] = xc[offk[k]] * mk[k];
        const float4* wr = (const float4*)&wch[c * 180];
        #pragma unroll
        for (int k = 0; k < 9; ++k) {
            #pragma unroll
            for (int o4 = 0; o4 < 5; ++o4) {
                float4 wv4 = wr[k * 5 + o4];
                acc[o4*4+0] = fmaf(xv[k], wv4.x, acc[o4*4+0]);
                acc[o4*4+1] = fmaf(xv[k], wv4.y, acc[o4*4+1]);
                acc[o4*4+2] = fmaf(xv[k], wv4.z, acc[o4*4+2]);
                acc[o4*4+3] = fmaf(xv[k], wv4.w, acc[o4*4+3]);
            }
        }
    }
    float* pp = part + (size_t)(cc * BN + b) * 18 * HW + rem;
    #pragma unroll
    for (int o = 0; o < 18; ++o) pp[(size_t)o * HW] = acc[o];
}

// Fused bilinear sampling (channel-last, coalesced) + bf16 MFMA GEMM.
// Block = 32 positions x 256 oc. Wave = one (pos,tap) record, lane = channel.
__global__ void __launch_bounds__(256)
deform_mfma_kernel(const unsigned short* __restrict__ xT, const float* __restrict__ part,
                   const float* __restrict__ ob, const unsigned short* __restrict__ wB,
                   const float* __restrict__ db, float* __restrict__ out) {
    __shared__ __align__(16) unsigned short sam[MPOS * SAMW];   // 37376 B, reused as cT
    __shared__ float offs[MPOS][18];
    __shared__ __align__(16) float taps[MPOS * 9 * 8];          // 9216 B
    const int tid = threadIdx.x;
    int blk = (int)blockIdx.x;
    blk = (blk & 7) * (NBLK / 8) + (blk >> 3);   // XCD swizzle
    const int pos0 = blk * MPOS;
    const int b0   = pos0 / HW;
    const int rem0 = pos0 - b0 * HW;
    const int h0   = rem0 / WW;
    const int w0   = rem0 - h0 * WW;             // w0 % 32 == 0

    // offsets: sum 8 partial chunks + bias
    for (int i = tid; i < MPOS * 18; i += 256) {
        int p = i / 18, oc = i - 18 * p;
        float s = ob[oc];
        #pragma unroll
        for (int cc = 0; cc < NOCHK; ++cc)
            s += part[((size_t)(cc * BN + b0) * 18 + oc) * HW + rem0 + p];
        offs[p][oc] = s;
    }
    __syncthreads();

    // ---- tap table: 288 (position, tap) records ----
    for (int rec = tid; rec < MPOS * 9; rec += 256) {
        int p  = rec / 9, t9 = rec - 9 * p;
        int ky = t9 / 3, kx = t9 - 3 * (t9 / 3);
        float py = (float)(h0 - 1 + ky) + offs[p][2 * t9];
        float px = (float)(w0 + p - 1 + kx) + offs[p][2 * t9 + 1];
        float yf = floorf(py), xf = floorf(px);
        int y0 = (int)yf, x0 = (int)xf;
        float wy1 = py - yf, wx1 = px - xf;
        float fy0 = ((unsigned)y0       < HH) ? 1.f - wy1 : 0.f;
        float fy1 = ((unsigned)(y0 + 1) < HH) ? wy1       : 0.f;
        float fx0 = ((unsigned)x0       < WW) ? 1.f - wx1 : 0.f;
        float fx1 = ((unsigned)(x0 + 1) < WW) ? wx1       : 0.f;
        int y0c = min(max(y0, 0), HH - 1), y1c = min(max(y0 + 1, 0), HH - 1);
        int x0c = min(max(x0, 0), WW - 1), x1c = min(max(x0 + 1, 0), WW - 1);
        int bx  = min(max(x0, 0), WW - 2);       // 2-col window [bx, bx+1]
        float wA  = (x0c == bx     ? fx0 : 0.f) + (x1c == bx     ? fx1 : 0.f);
        float wBv = (x0c == bx + 1 ? fx0 : 0.f) + (x1c == bx + 1 ? fx1 : 0.f);
        float* tv = taps + rec * 8;
        tv[0] = __int_as_float(y0c * WW + bx);
        tv[1] = __int_as_float(y1c * WW + bx);
        tv[2] = fy0 * wA;  tv[3] = fy0 * wBv;
        tv[4] = fy1 * wA;  tv[5] = fy1 * wBv;
        tv[6] = __int_as_float(p * SAMW + t9 * 64);   // LDS dst for this record
        tv[7] = 0.f;
    }

    const int lane = tid & 63;
    const int wv4  = tid >> 6;
    const int m    = tid & 15;
    const int q    = (tid >> 4) & 3;
    const int wv   = tid >> 6;

    f32x4 acc[2][4] = {};
    const unsigned short* xTb = xT + (size_t)b0 * HW * CH;

    for (int ck = 0; ck < NCK; ++ck) {
        __syncthreads();
        // ---- sampling: wave = record, lane = channel; 4 coalesced loads/record ----
        const unsigned short* xck = xTb + ck * CKCH + lane;
        #pragma unroll 4
        for (int rr = 0; rr < 72; ++rr) {
            int rec = 4 * rr + wv4;
            const float* tv = taps + rec * 8;
            float4 t0 = *(const float4*)tv;
            float4 t1 = *(const float4*)(tv + 4);
            int i0  = __float_as_int(t0.x);
            int i1  = __float_as_int(t0.y);
            int dso = __float_as_int(t1.z);
            const unsigned short* pA = xck + (size_t)i0 * CH;
            const unsigned short* pC = xck + (size_t)i1 * CH;
            float v = bf2f(pA[0])  * t0.z + bf2f(pA[CH]) * t0.w
                    + bf2f(pC[0])  * t1.x + bf2f(pC[CH]) * t1.y;
            sam[dso + lane] = f2bf(v);
        }
        __syncthreads();
        // ---- GEMM on this chunk: 18 k-tiles of 32, 2 m-tiles ----
        const unsigned short* wpg = wB + (size_t)(ck * 72 + q) * (256 * 8);
        const unsigned short* arow0 = sam + m * SAMW + q * 8;
        const unsigned short* arow1 = arow0 + 16 * SAMW;
        for (int kb = 0; kb < 18; ++kb) {
            short8 av0 = *(const short8*)(arow0 + kb * 32);
            short8 av1 = *(const short8*)(arow1 + kb * 32);
            const unsigned short* wkb = wpg + (size_t)kb * (4 * 256 * 8)
                                       + (size_t)(wv * 64 + m) * 8;
            #pragma unroll
            for (int t = 0; t < 4; ++t) {
                short8 bv = *(const short8*)(wkb + t * 16 * 8);
                acc[0][t] = __builtin_amdgcn_mfma_f32_16x16x32_bf16(av0, bv, acc[0][t], 0, 0, 0);
                acc[1][t] = __builtin_amdgcn_mfma_f32_16x16x32_bf16(av1, bv, acc[1][t], 0, 0, 0);
            }
        }
    }

    // ---- epilogue: LDS transpose, coalesced stores ----
    __syncthreads();
    float* cT = (float*)sam;   // [256][33] f32 = 33792 B <= 37376
    #pragma unroll
    for (int mt = 0; mt < 2; ++mt)
        #pragma unroll
        for (int t = 0; t < 4; ++t) {
            int oc = wv * 64 + t * 16 + m;
            #pragma unroll
            for (int r = 0; r < 4; ++r)
                cT[oc * 33 + mt * 16 + q * 4 + r] = acc[mt][t][r];
        }
    __syncthreads();
    const int p_o = tid & 31;
    const int og  = tid >> 5;
    float* op = out + ((size_t)b0 * CH) * HW + rem0 + p_o;
    #pragma unroll 4
    for (int i = 0; i < 32; ++i) {
        int oc = og * 32 + i;
        op[(size_t)oc * HW] = fmaxf(cT[oc * 33 + p_o] + db[oc], 0.f);
    }
}

extern "C" void kernel_launch(void* const* d_in, const int* in_sizes, int n_in,
                              void* d_out, int out_size, void* d_ws, size_t ws_size,
                              hipStream_t stream) {
    const float* x     = (const float*)d_in[0];
    const float* off_w = (const float*)d_in[1];
    const float* off_b = (const float*)d_in[2];
    const float* dw    = (const float*)d_in[3];
    const float* db    = (const float*)d_in[4];

    float* ws   = (float*)d_ws;
    float* part = ws;                                        // 8*BN*18*HW
    float* buf0 = part + (size_t)NOCHK * BN * 18 * HW;       // BN*CH*HW
    float* buf1 = buf0 + (size_t)BN * CH * HW;               // BN*CH*HW
    float* owT  = buf1 + (size_t)BN * CH * HW;               // OWT_TOT
    unsigned short* wB = (unsigned short*)(owT + OWT_TOT);   // WB_TOT bf16
    unsigned short* xT = wB + WB_TOT;                        // BN*HW*CH bf16

    prep_kernel<<<(WB_TOT + OWT_TOT + 255) / 256, 256, 0, stream>>>(dw, off_w, wB, owT);

    const float* cur = x;
    for (int l = 0; l < NL; ++l) {
        float* nxt = (l == NL - 1) ? (float*)d_out : ((l & 1) ? buf1 : buf0);
        off_conv2_kernel<<<72 * NOCHK, 256, 0, stream>>>(
            cur, owT + (size_t)l * OWT_PER_L, part);
        transpose_kernel<<<BN * 576, 256, 0, stream>>>(cur, xT);
        deform_mfma_kernel<<<NBLK, 256, 0, stream>>>(
            xT, part, off_b + l * 18, wB + (size_t)l * WB_PER_L, db + l * CH, nxt);
        cur = nxt;
    }
}

// Round 7
// 524.269 us; speedup vs baseline: 1.7377x; 1.1127x over previous
//
#include <hip/hip_runtime.h>

#define BN 2
#define CH 256
#define HH 96
#define WW 96
#define NL 4
#define HW (HH*WW)        // 9216
#define KK (CH*9)         // 2304
#define NPOS (BN*HW)      // 18432

#define MPOS 32           // positions per block
#define NBLK (NPOS/MPOS)  // 576 position-blocks (x2 splits = 1152 blocks)
#define CKCH 32           // channels per K-chunk
#define CKLEN (CKCH*9)    // 288 cols per chunk
#define NCKS 4            // chunks per split (split covers 128 channels)
#define SAMW2 296         // ushort row stride: 592 B = 37 x 16B

#define NOCHK 8           // off-conv channel chunks
#define OCCH (CH/NOCHK)   // 32

#define WB_PER_L (288*256*8)   // bf16/layer, [g][oc][j], permuted cols
#define WB_TOT (NL*WB_PER_L)
#define OWT_PER_L (KK*20)
#define OWT_TOT (NL*OWT_PER_L)

typedef __attribute__((ext_vector_type(8))) short short8;
typedef __attribute__((ext_vector_type(4))) float f32x4;

__device__ __forceinline__ unsigned short f2bf(float f) {
    union { float f; unsigned int u; } v; v.f = f;
    unsigned int r = v.u + 0x7fffu + ((v.u >> 16) & 1u);
    return (unsigned short)(r >> 16);
}

// Pack dw -> wB (bf16, B-frag order over PERMUTED cols) and off_w -> owT.
// Permuted column: col = ck*288 + t9*32 + ci, channel c = ck*32 + ci.
__global__ void prep_kernel(const float* __restrict__ dw, const float* __restrict__ off_w,
                            unsigned short* __restrict__ wB, float* __restrict__ owT) {
    int idx = blockIdx.x * 256 + threadIdx.x;
    if (idx < WB_TOT) {
        int j  = idx & 7;
        int oc = (idx >> 3) & 255;
        int g  = (idx >> 11) % 288;
        int l  = idx / WB_PER_L;
        int col = g * 8 + j;
        int ck = col / CKLEN;
        int r  = col - ck * CKLEN;
        int t9 = r >> 5;
        int ci = r & 31;
        int c  = ck * CKCH + ci;
        wB[idx] = f2bf(dw[((size_t)(l * CH + oc) * CH + c) * 9 + t9]);
    } else {
        int i2 = idx - WB_TOT;
        if (i2 >= OWT_TOT) return;
        int ocp = i2 % 20;
        int r   = (i2 / 20) % KK;
        int l   = i2 / OWT_PER_L;
        int c   = r / 9, t9 = r - 9 * c;
        owT[i2] = (ocp < 18) ? off_w[((size_t)(l * 18 + ocp) * CH + c) * 9 + t9] : 0.f;
    }
}

// NCHW f32 -> channel-last bf16: xT[b][hw][c]. 64x64 LDS tile transpose.
__global__ void __launch_bounds__(256)
transpose_kernel(const float* __restrict__ src, unsigned short* __restrict__ xT) {
    __shared__ float tile[64][65];
    int blk = blockIdx.x;
    int b = blk / 576, r = blk - 576 * b;
    int hw0 = (r >> 2) * 64, c0 = (r & 3) * 64;
    int tid = threadIdx.x;
    int lane = tid & 63, grp = tid >> 6;
    const float* sp = src + (size_t)(b * CH + c0) * HW + hw0;
    #pragma unroll
    for (int i = 0; i < 16; ++i) {
        int c = grp * 16 + i;
        tile[c][lane] = sp[(size_t)c * HW + lane];
    }
    __syncthreads();
    unsigned short* dp = xT + (size_t)(b * HW + hw0) * CH + c0;
    #pragma unroll
    for (int i = 0; i < 16; ++i) {
        int hw = grp * 16 + i;
        dp[(size_t)hw * CH + lane] = f2bf(tile[lane][hw]);
    }
}

// Offset conv, partial over 32-channel chunk. grid = 72 pos-blocks * 8 chunks.
__global__ void __launch_bounds__(256)
off_conv2_kernel(const float* __restrict__ x, const float* __restrict__ owT,
                 float* __restrict__ part) {
    __shared__ __align__(16) float wch[OCCH * 180];
    const int pb = blockIdx.x >> 3;
    const int cc = blockIdx.x & 7;
    const int tid = threadIdx.x;
    for (int i = tid; i < OCCH * 180; i += 256)
        wch[i] = owT[(size_t)(cc * OCCH) * 180 + i];

    const int pos = pb * 256 + tid;
    const int b = pos / HW, rem = pos - b * HW;
    const int h = rem / WW, w = rem - h * WW;
    int offk[9]; float mk[9];
    #pragma unroll
    for (int k = 0; k < 9; ++k) {
        int dy = k / 3 - 1, dx = k % 3 - 1;
        int yk = h + dy, xk = w + dx;
        bool valid = ((unsigned)yk < HH) && ((unsigned)xk < WW);
        offk[k] = min(max(yk, 0), HH - 1) * WW + min(max(xk, 0), WW - 1);
        mk[k] = valid ? 1.f : 0.f;
    }
    float acc[20];
    #pragma unroll
    for (int o = 0; o < 20; ++o) acc[o] = 0.f;
    __syncthreads();

    const float* xc = x + (size_t)(b * CH + cc * OCCH) * HW;
    for (int c = 0; c < OCCH; ++c, xc += HW) {
        float xv[9];
        #pragma unroll
        for (int k = 0; k < 9; ++k) xv[k] = xc[offk[k]] * mk[k];
        const float4* wr = (const float4*)&wch[c * 180];
        #pragma unroll
        for (int k = 0; k < 9; ++k) {
            #pragma unroll
            for (int o4 = 0; o4 < 5; ++o4) {
                float4 wv4 = wr[k * 5 + o4];
                acc[o4*4+0] = fmaf(xv[k], wv4.x, acc[o4*4+0]);
                acc[o4*4+1] = fmaf(xv[k], wv4.y, acc[o4*4+1]);
                acc[o4*4+2] = fmaf(xv[k], wv4.z, acc[o4*4+2]);
                acc[o4*4+3] = fmaf(xv[k], wv4.w, acc[o4*4+3]);
            }
        }
    }
    float* pp = part + (size_t)(cc * BN + b) * 18 * HW + rem;
    #pragma unroll
    for (int o = 0; o < 18; ++o) pp[(size_t)o * HW] = acc[o];
}

// Split-K fused sampling + MFMA. bid = pos-block*2 + split.
// Split s covers channels [s*128, s*128+128) as 4 chunks of 32.
// Sampling: 16 lanes per record (lane = channel pair), 4 records/wave-iter.
__global__ void __launch_bounds__(256, 4)
deform_mfma_kernel(const unsigned short* __restrict__ xT, const float* __restrict__ part,
                   const float* __restrict__ ob, const unsigned short* __restrict__ wB,
                   float* __restrict__ dst0, float* __restrict__ dst1) {
    __shared__ __align__(16) unsigned short sam[MPOS * SAMW2];  // 18944 B, reused as cT
    __shared__ float offs[MPOS][18];                            // 2304 B
    __shared__ __align__(16) float taps[MPOS * 9 * 8];          // 9216 B
    const int tid = threadIdx.x;
    const int s   = (int)blockIdx.x & 1;
    int pb = (int)blockIdx.x >> 1;
    pb = (pb & 7) * (NBLK / 8) + (pb >> 3);      // XCD swizzle
    const int pos0 = pb * MPOS;
    const int b0   = pos0 / HW;
    const int rem0 = pos0 - b0 * HW;
    const int h0   = rem0 / WW;
    const int w0   = rem0 - h0 * WW;             // w0 % 32 == 0

    // offsets: sum 8 partial chunks + bias
    for (int i = tid; i < MPOS * 18; i += 256) {
        int p = i / 18, oc = i - 18 * p;
        float ssum = ob[oc];
        #pragma unroll
        for (int cc = 0; cc < NOCHK; ++cc)
            ssum += part[((size_t)(cc * BN + b0) * 18 + oc) * HW + rem0 + p];
        offs[p][oc] = ssum;
    }
    __syncthreads();

    // ---- tap table: 288 (position, tap) records ----
    for (int rec = tid; rec < MPOS * 9; rec += 256) {
        int p  = rec / 9, t9 = rec - 9 * p;
        int ky = t9 / 3, kx = t9 - 3 * (t9 / 3);
        float py = (float)(h0 - 1 + ky) + offs[p][2 * t9];
        float px = (float)(w0 + p - 1 + kx) + offs[p][2 * t9 + 1];
        float yf = floorf(py), xf = floorf(px);
        int y0 = (int)yf, x0 = (int)xf;
        float wy1 = py - yf, wx1 = px - xf;
        float fy0 = ((unsigned)y0       < HH) ? 1.f - wy1 : 0.f;
        float fy1 = ((unsigned)(y0 + 1) < HH) ? wy1       : 0.f;
        float fx0 = ((unsigned)x0       < WW) ? 1.f - wx1 : 0.f;
        float fx1 = ((unsigned)(x0 + 1) < WW) ? wx1       : 0.f;
        int y0c = min(max(y0, 0), HH - 1), y1c = min(max(y0 + 1, 0), HH - 1);
        int x0c = min(max(x0, 0), WW - 1), x1c = min(max(x0 + 1, 0), WW - 1);
        int bx  = min(max(x0, 0), WW - 2);       // 2-col window [bx, bx+1]
        float wA  = (x0c == bx     ? fx0 : 0.f) + (x1c == bx     ? fx1 : 0.f);
        float wBv = (x0c == bx + 1 ? fx0 : 0.f) + (x1c == bx + 1 ? fx1 : 0.f);
        float* tv = taps + rec * 8;
        tv[0] = __int_as_float((y0c * WW + bx) * CH);   // element offsets in xT row-space
        tv[1] = __int_as_float((y1c * WW + bx) * CH);
        tv[2] = fy0 * wA;  tv[3] = fy0 * wBv;           // (y0,bx) (y0,bx+1)
        tv[4] = fy1 * wA;  tv[5] = fy1 * wBv;           // (y1,bx) (y1,bx+1)
        tv[6] = __int_as_float(p * SAMW2 + t9 * 32);    // LDS dst (elems)
        tv[7] = 0.f;
    }

    const int lane = tid & 63;
    const int wvi  = tid >> 6;
    const int cp   = lane & 15;      // channel pair within chunk
    const int rsub = lane >> 4;      // record sub-slot
    const int m    = tid & 15;
    const int q    = (tid >> 4) & 3;

    f32x4 acc[2][4] = {};
    const unsigned short* xTb = xT + (size_t)b0 * HW * CH;

    for (int ckl = 0; ckl < NCKS; ++ckl) {
        const int ck = s * NCKS + ckl;           // global chunk 0..7
        __syncthreads();
        // ---- sampling ----
        const unsigned short* xs = xTb + ck * CKCH + cp * 2;
        #pragma unroll 2
        for (int rr = 0; rr < 18; ++rr) {
            int rec = wvi * 72 + rr * 4 + rsub;
            const float* tv = taps + rec * 8;
            float4 t0 = *(const float4*)tv;
            float4 t1 = *(const float4*)(tv + 4);
            int i0  = __float_as_int(t0.x);
            int i1  = __float_as_int(t0.y);
            int dso = __float_as_int(t1.z);
            unsigned int A0, A1, C0, C1;
            __builtin_memcpy(&A0, xs + i0, 4);
            __builtin_memcpy(&A1, xs + i0 + CH, 4);
            __builtin_memcpy(&C0, xs + i1, 4);
            __builtin_memcpy(&C1, xs + i1 + CH, 4);
            float vl = __uint_as_float(A0 << 16) * t0.z
                     + __uint_as_float(A1 << 16) * t0.w
                     + __uint_as_float(C0 << 16) * t1.x
                     + __uint_as_float(C1 << 16) * t1.y;
            float vh = __uint_as_float(A0 & 0xFFFF0000u) * t0.z
                     + __uint_as_float(A1 & 0xFFFF0000u) * t0.w
                     + __uint_as_float(C0 & 0xFFFF0000u) * t1.x
                     + __uint_as_float(C1 & 0xFFFF0000u) * t1.y;
            unsigned int packed = (unsigned int)f2bf(vl) | ((unsigned int)f2bf(vh) << 16);
            *(unsigned int*)(sam + dso + cp * 2) = packed;
        }
        __syncthreads();
        // ---- GEMM on this chunk: 9 k-tiles of 32, 2 m-tiles ----
        const unsigned short* arow0 = sam + m * SAMW2 + q * 8;
        const unsigned short* arow1 = arow0 + 16 * SAMW2;
        const int g0 = ck * 36;
        for (int kb = 0; kb < 9; ++kb) {
            short8 av0 = *(const short8*)(arow0 + kb * 32);
            short8 av1 = *(const short8*)(arow1 + kb * 32);
            const unsigned short* wkb = wB + ((size_t)(g0 + kb * 4 + q) * 256
                                             + (wvi * 64 + m)) * 8;
            #pragma unroll
            for (int t = 0; t < 4; ++t) {
                short8 bv = *(const short8*)(wkb + t * 16 * 8);
                acc[0][t] = __builtin_amdgcn_mfma_f32_16x16x32_bf16(av0, bv, acc[0][t], 0, 0, 0);
                acc[1][t] = __builtin_amdgcn_mfma_f32_16x16x32_bf16(av1, bv, acc[1][t], 0, 0, 0);
            }
        }
    }

    // ---- epilogue: raw partials (no bias/relu), two 16-pos passes ----
    float* dst = s ? dst1 : dst0;
    float* cT = (float*)sam;                 // [256][17] f32 = 17408 B <= 18944
    #pragma unroll
    for (int mt = 0; mt < 2; ++mt) {
        __syncthreads();
        #pragma unroll
        for (int t = 0; t < 4; ++t) {
            int oc = wvi * 64 + t * 16 + m;
            #pragma unroll
            for (int r = 0; r < 4; ++r)
                cT[oc * 17 + q * 4 + r] = acc[mt][t][r];
        }
        __syncthreads();
        const int p_o = tid & 15;
        const int og  = tid >> 4;
        #pragma unroll 4
        for (int i = 0; i < 16; ++i) {
            int oc = og * 16 + i;
            dst[((size_t)(b0 * CH) + oc) * HW + rem0 + mt * 16 + p_o] = cT[oc * 17 + p_o];
        }
    }
}

// out = relu(p0 + p1 + bias), in place over p0. float4 over BN*CH*HW.
__global__ void __launch_bounds__(256)
ep_kernel(float* __restrict__ p0, const float* __restrict__ p1,
          const float* __restrict__ db) {
    unsigned int idx = blockIdx.x * 256 + threadIdx.x;   // float4 index
    unsigned int oc = (idx / (HW / 4)) & (CH - 1);
    float bsv = db[oc];
    float4 a = ((const float4*)p0)[idx];
    float4 b = ((const float4*)p1)[idx];
    float4 o;
    o.x = fmaxf(a.x + b.x + bsv, 0.f);
    o.y = fmaxf(a.y + b.y + bsv, 0.f);
    o.z = fmaxf(a.z + b.z + bsv, 0.f);
    o.w = fmaxf(a.w + b.w + bsv, 0.f);
    ((float4*)p0)[idx] = o;
}

extern "C" void kernel_launch(void* const* d_in, const int* in_sizes, int n_in,
                              void* d_out, int out_size, void* d_ws, size_t ws_size,
                              hipStream_t stream) {
    const float* x     = (const float*)d_in[0];
    const float* off_w = (const float*)d_in[1];
    const float* off_b = (const float*)d_in[2];
    const float* dw    = (const float*)d_in[3];
    const float* db    = (const float*)d_in[4];

    float* ws   = (float*)d_ws;
    float* part = ws;                                        // 8*BN*18*HW
    float* buf0 = part + (size_t)NOCHK * BN * 18 * HW;       // BN*CH*HW
    float* buf1 = buf0 + (size_t)BN * CH * HW;               // BN*CH*HW
    float* p1   = buf1 + (size_t)BN * CH * HW;               // BN*CH*HW (split-1 partial)
    float* owT  = p1 + (size_t)BN * CH * HW;                 // OWT_TOT
    unsigned short* wB = (unsigned short*)(owT + OWT_TOT);   // WB_TOT bf16
    unsigned short* xT = wB + WB_TOT;                        // BN*HW*CH bf16

    prep_kernel<<<(WB_TOT + OWT_TOT + 255) / 256, 256, 0, stream>>>(dw, off_w, wB, owT);

    const float* cur = x;
    for (int l = 0; l < NL; ++l) {
        float* nxt = (l == NL - 1) ? (float*)d_out : ((l & 1) ? buf1 : buf0);
        off_conv2_kernel<<<72 * NOCHK, 256, 0, stream>>>(
            cur, owT + (size_t)l * OWT_PER_L, part);
        transpose_kernel<<<BN * 576, 256, 0, stream>>>(cur, xT);
        deform_mfma_kernel<<<NBLK * 2, 256, 0, stream>>>(
            xT, part, off_b + l * 18, wB + (size_t)l * WB_PER_L, nxt, p1);
        ep_kernel<<<(BN * CH * HW / 4) / 256, 256, 0, stream>>>(nxt, p1, db + l * CH);
        cur = nxt;
    }
}

// Round 8
// 493.330 us; speedup vs baseline: 1.8466x; 1.0627x over previous
//
#include <hip/hip_runtime.h>

#define BN 2
#define CH 256
#define HH 96
#define WW 96
#define NL 4
#define HW (HH*WW)        // 9216
#define KK (CH*9)         // 2304
#define NPOS (BN*HW)      // 18432

#define MPOS 32           // positions per block
#define NBLK (NPOS/MPOS)  // 576 position-blocks
#define CKCH 32           // channels per K-chunk
#define CKLEN (CKCH*9)    // 288 cols per chunk
#define NCKS 4            // chunks per split (split = 128 channels)
#define SAMW2 296         // ushort row stride: 592 B

#define WB_PER_L (288*256*8)    // main weights bf16/layer
#define WB_TOT (NL*WB_PER_L)
#define OWB_PER_L (288*32*8)    // off weights bf16/layer (N padded to 32)
#define OWB_TOT (NL*OWB_PER_L)

typedef __attribute__((ext_vector_type(8))) short short8;
typedef __attribute__((ext_vector_type(4))) float f32x4;

__device__ __forceinline__ unsigned short f2bf(float f) {
    union { float f; unsigned int u; } v; v.f = f;
    unsigned int r = v.u + 0x7fffu + ((v.u >> 16) & 1u);
    return (unsigned short)(r >> 16);
}

// Pack dw -> wB and off_w -> owB (both bf16 B-frag order over permuted cols).
// Permuted column: col = ck*288 + t9*32 + ci, channel c = ck*32 + ci.
__global__ void prep_kernel(const float* __restrict__ dw, const float* __restrict__ off_w,
                            unsigned short* __restrict__ wB, unsigned short* __restrict__ owB) {
    int idx = blockIdx.x * 256 + threadIdx.x;
    if (idx < WB_TOT) {
        int j  = idx & 7;
        int oc = (idx >> 3) & 255;
        int g  = (idx >> 11) % 288;
        int l  = idx / WB_PER_L;
        int col = g * 8 + j;
        int ck = col / CKLEN;
        int r  = col - ck * CKLEN;
        int t9 = r >> 5;
        int ci = r & 31;
        int c  = ck * CKCH + ci;
        wB[idx] = f2bf(dw[((size_t)(l * CH + oc) * CH + c) * 9 + t9]);
    } else {
        int i2 = idx - WB_TOT;
        if (i2 >= OWB_TOT) return;
        int j   = i2 & 7;
        int ocp = (i2 >> 3) & 31;
        int g   = (i2 >> 8) % 288;
        int l   = i2 / OWB_PER_L;
        int col = g * 8 + j;
        int ck = col / CKLEN;
        int r  = col - ck * CKLEN;
        int t9 = r >> 5;
        int ci = r & 31;
        int c  = ck * CKCH + ci;
        owB[i2] = (ocp < 18) ? f2bf(off_w[((size_t)(l * 18 + ocp) * CH + c) * 9 + t9]) : 0;
    }
}

// Layer-0 only: NCHW f32 -> channel-last bf16 xT[b][hw][c].
__global__ void __launch_bounds__(256)
transpose_kernel(const float* __restrict__ src, unsigned short* __restrict__ xT) {
    __shared__ float tile[64][65];
    int blk = blockIdx.x;
    int b = blk / 576, r = blk - 576 * b;
    int hw0 = (r >> 2) * 64, c0 = (r & 3) * 64;
    int tid = threadIdx.x;
    int lane = tid & 63, grp = tid >> 6;
    const float* sp = src + (size_t)(b * CH + c0) * HW + hw0;
    #pragma unroll
    for (int i = 0; i < 16; ++i) {
        int c = grp * 16 + i;
        tile[c][lane] = sp[(size_t)c * HW + lane];
    }
    __syncthreads();
    unsigned short* dp = xT + (size_t)(b * HW + hw0) * CH + c0;
    #pragma unroll
    for (int i = 0; i < 16; ++i) {
        int hw = grp * 16 + i;
        dp[(size_t)hw * CH + lane] = f2bf(tile[lane][hw]);
    }
}

// Offset conv as MFMA: M=32 pos, N=32 (18 live), K=2304 in 8 chunks.
// A staged from xT by masked shifted copies. Writes off_g[pos][18] (bias folded).
__global__ void __launch_bounds__(256)
off_mfma_kernel(const unsigned short* __restrict__ xT, const unsigned short* __restrict__ owB,
                const float* __restrict__ ob, float* __restrict__ off_g) {
    __shared__ __align__(16) unsigned short sam[MPOS * SAMW2];   // 18944 B
    __shared__ int rtab[288 * 2];
    const int tid = threadIdx.x;
    int pb = (int)blockIdx.x;
    pb = (pb & 7) * (NBLK / 8) + (pb >> 3);      // XCD swizzle
    const int pos0 = pb * MPOS;
    const int b0   = pos0 / HW;
    const int rem0 = pos0 - b0 * HW;
    const int h0   = rem0 / WW;
    const int w0   = rem0 - h0 * WW;

    for (int rec = tid; rec < 288; rec += 256) {
        int p = rec / 9, t9 = rec - 9 * p;
        int dy = t9 / 3 - 1, dx = t9 - 3 * (t9 / 3) - 1;
        int y = h0 + dy, xw = w0 + p + dx;
        bool valid = ((unsigned)y < HH) && ((unsigned)xw < WW);
        rtab[2 * rec]     = valid ? (y * WW + xw) * CH : -1;
        rtab[2 * rec + 1] = p * SAMW2 + t9 * 32;
    }

    const int m   = tid & 15;
    const int q   = (tid >> 4) & 3;
    const int wvi = tid >> 6;
    const int mt  = wvi & 1;          // A row base mt*16
    const int nt  = wvi >> 1;         // oc base nt*16
    f32x4 aoff = {};
    const unsigned short* xTb = xT + (size_t)b0 * HW * CH;

    for (int ck = 0; ck < 8; ++ck) {
        __syncthreads();
        #pragma unroll
        for (int i = 0; i < 18; ++i) {          // 4608 dwords
            int slot = i * 256 + tid;
            int rec = slot >> 4, cp = slot & 15;
            int s0 = rtab[2 * rec];
            int d0 = rtab[2 * rec + 1];
            unsigned int v = 0;
            if (s0 >= 0) __builtin_memcpy(&v, xTb + s0 + ck * CKCH + cp * 2, 4);
            *(unsigned int*)(sam + d0 + cp * 2) = v;
        }
        __syncthreads();
        const unsigned short* arow = sam + (mt * 16 + m) * SAMW2 + q * 8;
        #pragma unroll
        for (int kb = 0; kb < 9; ++kb) {
            short8 av = *(const short8*)(arow + kb * 32);
            short8 bv = *(const short8*)(owB + ((size_t)((ck * 36 + kb * 4 + q) * 32)
                                                + nt * 16 + m) * 8);
            aoff = __builtin_amdgcn_mfma_f32_16x16x32_bf16(av, bv, aoff, 0, 0, 0);
        }
    }
    // D: row(pos) = q*4+r, col(oc) = m
    int oc = nt * 16 + m;
    if (oc < 18) {
        float bsv = ob[oc];
        #pragma unroll
        for (int r = 0; r < 4; ++r) {
            int p = mt * 16 + q * 4 + r;
            off_g[(size_t)(pos0 + p) * 18 + oc] = aoff[r] + bsv;
        }
    }
}

// Split-K fused sampling + MFMA. bid = pos-block*2 + split.
// Writes channel-last f32 partials pCL[pos][256].
__global__ void __launch_bounds__(256, 5)
deform_mfma_kernel(const unsigned short* __restrict__ xT, const float* __restrict__ off_g,
                   const unsigned short* __restrict__ wB,
                   float* __restrict__ dst0, float* __restrict__ dst1) {
    __shared__ __align__(16) unsigned short sam[MPOS * SAMW2];  // 18944 B, reused as cT
    __shared__ float offs[MPOS * 18];                           // 2304 B
    __shared__ __align__(16) uint4 taps4[MPOS * 9];             // 4608 B
    __shared__ unsigned short dso16[MPOS * 9];                  // 576 B
    const int tid = threadIdx.x;
    const int s   = (int)blockIdx.x & 1;
    int pb = (int)blockIdx.x >> 1;
    pb = (pb & 7) * (NBLK / 8) + (pb >> 3);      // XCD swizzle
    const int pos0 = pb * MPOS;
    const int b0   = pos0 / HW;
    const int rem0 = pos0 - b0 * HW;
    const int h0   = rem0 / WW;
    const int w0   = rem0 - h0 * WW;

    for (int i = tid; i < MPOS * 18; i += 256)
        offs[i] = off_g[(size_t)pos0 * 18 + i];
    __syncthreads();

    // ---- tap table: 288 records, packed to one uint4 + ushort dso ----
    for (int rec = tid; rec < MPOS * 9; rec += 256) {
        int p  = rec / 9, t9 = rec - 9 * p;
        int ky = t9 / 3, kx = t9 - 3 * (t9 / 3);
        float py = (float)(h0 - 1 + ky) + offs[p * 18 + 2 * t9];
        float px = (float)(w0 + p - 1 + kx) + offs[p * 18 + 2 * t9 + 1];
        float yf = floorf(py), xf = floorf(px);
        int y0 = (int)yf, x0 = (int)xf;
        float wy1 = py - yf, wx1 = px - xf;
        float fy0 = ((unsigned)y0       < HH) ? 1.f - wy1 : 0.f;
        float fy1 = ((unsigned)(y0 + 1) < HH) ? wy1       : 0.f;
        float fx0 = ((unsigned)x0       < WW) ? 1.f - wx1 : 0.f;
        float fx1 = ((unsigned)(x0 + 1) < WW) ? wx1       : 0.f;
        int y0c = min(max(y0, 0), HH - 1), y1c = min(max(y0 + 1, 0), HH - 1);
        int x0c = min(max(x0, 0), WW - 1), x1c = min(max(x0 + 1, 0), WW - 1);
        int bx  = min(max(x0, 0), WW - 2);
        float wA  = (x0c == bx     ? fx0 : 0.f) + (x1c == bx     ? fx1 : 0.f);
        float wBv = (x0c == bx + 1 ? fx0 : 0.f) + (x1c == bx + 1 ? fx1 : 0.f);
        uint4 tv;
        tv.x = (unsigned int)((y0c * WW + bx) * CH);
        tv.y = (unsigned int)((y1c * WW + bx) * CH);
        tv.z = (unsigned int)f2bf(fy0 * wA) | ((unsigned int)f2bf(fy0 * wBv) << 16);
        tv.w = (unsigned int)f2bf(fy1 * wA) | ((unsigned int)f2bf(fy1 * wBv) << 16);
        taps4[rec] = tv;
        dso16[rec] = (unsigned short)(p * SAMW2 + t9 * 32);
    }

    const int lane = tid & 63;
    const int wvi  = tid >> 6;
    const int cp   = lane & 15;      // channel pair within chunk
    const int rsub = lane >> 4;      // record sub-slot
    const int m    = tid & 15;
    const int q    = (tid >> 4) & 3;

    f32x4 acc[2][4] = {};
    const unsigned short* xTb = xT + (size_t)b0 * HW * CH;

    for (int ckl = 0; ckl < NCKS; ++ckl) {
        const int ck = s * NCKS + ckl;
        __syncthreads();
        const unsigned short* xs = xTb + ck * CKCH + cp * 2;
        #pragma unroll 3
        for (int rr = 0; rr < 18; ++rr) {
            int rec = wvi * 72 + rr * 4 + rsub;
            uint4 tv = taps4[rec];
            int dso  = dso16[rec];
            float u0 = __uint_as_float(tv.z << 16);
            float u1 = __uint_as_float(tv.z & 0xFFFF0000u);
            float u2 = __uint_as_float(tv.w << 16);
            float u3 = __uint_as_float(tv.w & 0xFFFF0000u);
            unsigned int A0, A1, C0, C1;
            __builtin_memcpy(&A0, xs + tv.x, 4);
            __builtin_memcpy(&A1, xs + tv.x + CH, 4);
            __builtin_memcpy(&C0, xs + tv.y, 4);
            __builtin_memcpy(&C1, xs + tv.y + CH, 4);
            float vl = __uint_as_float(A0 << 16) * u0
                     + __uint_as_float(A1 << 16) * u1
                     + __uint_as_float(C0 << 16) * u2
                     + __uint_as_float(C1 << 16) * u3;
            float vh = __uint_as_float(A0 & 0xFFFF0000u) * u0
                     + __uint_as_float(A1 & 0xFFFF0000u) * u1
                     + __uint_as_float(C0 & 0xFFFF0000u) * u2
                     + __uint_as_float(C1 & 0xFFFF0000u) * u3;
            unsigned int packed = (unsigned int)f2bf(vl) | ((unsigned int)f2bf(vh) << 16);
            *(unsigned int*)(sam + dso + cp * 2) = packed;
        }
        __syncthreads();
        const unsigned short* arow0 = sam + m * SAMW2 + q * 8;
        const unsigned short* arow1 = arow0 + 16 * SAMW2;
        const int g0 = ck * 36;
        for (int kb = 0; kb < 9; ++kb) {
            short8 av0 = *(const short8*)(arow0 + kb * 32);
            short8 av1 = *(const short8*)(arow1 + kb * 32);
            const unsigned short* wkb = wB + ((size_t)(g0 + kb * 4 + q) * 256
                                             + (wvi * 64 + m)) * 8;
            #pragma unroll
            for (int t = 0; t < 4; ++t) {
                short8 bv = *(const short8*)(wkb + t * 16 * 8);
                acc[0][t] = __builtin_amdgcn_mfma_f32_16x16x32_bf16(av0, bv, acc[0][t], 0, 0, 0);
                acc[1][t] = __builtin_amdgcn_mfma_f32_16x16x32_bf16(av1, bv, acc[1][t], 0, 0, 0);
            }
        }
    }

    // ---- epilogue: channel-last partials pCL[pos][256] ----
    float* dst = s ? dst1 : dst0;
    float* cT = (float*)sam;                 // [256][17] f32 = 17408 B
    #pragma unroll
    for (int mt = 0; mt < 2; ++mt) {
        __syncthreads();
        #pragma unroll
        for (int t = 0; t < 4; ++t) {
            int oc = wvi * 64 + t * 16 + m;
            #pragma unroll
            for (int r = 0; r < 4; ++r)
                cT[oc * 17 + q * 4 + r] = acc[mt][t][r];
        }
        __syncthreads();
        float* dp = dst + (size_t)(pos0 + mt * 16) * CH + tid;
        #pragma unroll 4
        for (int p = 0; p < 16; ++p)
            dp[(size_t)p * CH] = cT[tid * 17 + p];
    }
}

// Layers 0-2 epilogue: xT = bf16(relu(p0 + p1 + bias)), channel-last (elementwise).
__global__ void __launch_bounds__(256)
sum_cl_kernel(const float* __restrict__ p0, const float* __restrict__ p1,
              const float* __restrict__ db, unsigned short* __restrict__ xT) {
    unsigned int idx = blockIdx.x * 256 + threadIdx.x;   // 4-elem group
    unsigned int e = idx * 4;
    unsigned int oc = e & (CH - 1);
    float4 bsv = *(const float4*)(db + oc);
    float4 a = *(const float4*)(p0 + e);
    float4 b = *(const float4*)(p1 + e);
    unsigned short o[4];
    o[0] = f2bf(fmaxf(a.x + b.x + bsv.x, 0.f));
    o[1] = f2bf(fmaxf(a.y + b.y + bsv.y, 0.f));
    o[2] = f2bf(fmaxf(a.z + b.z + bsv.z, 0.f));
    o[3] = f2bf(fmaxf(a.w + b.w + bsv.w, 0.f));
    __builtin_memcpy(xT + e, o, 8);
}

// Final layer epilogue: d_out(NCHW f32) = relu(p0 + p1 + bias), LDS transpose.
__global__ void __launch_bounds__(256)
sum_nchw_kernel(const float* __restrict__ p0, const float* __restrict__ p1,
                const float* __restrict__ db, float* __restrict__ out) {
    __shared__ float tile[64][65];
    int blk = blockIdx.x;
    int hw0 = (blk >> 2) * 64;            // flat pos base (never crosses batch)
    int oc0 = (blk & 3) * 64;
    int tid = threadIdx.x;
    int lane = tid & 63, grp = tid >> 6;
    float bsv = db[oc0 + lane];
    #pragma unroll
    for (int i = 0; i < 16; ++i) {
        int r = grp * 16 + i;
        size_t e = (size_t)(hw0 + r) * CH + oc0 + lane;
        tile[r][lane] = fmaxf(p0[e] + p1[e] + bsv, 0.f);
    }
    __syncthreads();
    int b = hw0 / HW, hwl = hw0 - b * HW;
    #pragma unroll
    for (int i = 0; i < 16; ++i) {
        int oc = grp * 16 + i;
        out[((size_t)(b * CH) + oc0 + oc) * HW + hwl + lane] = tile[lane][oc];
    }
}

extern "C" void kernel_launch(void* const* d_in, const int* in_sizes, int n_in,
                              void* d_out, int out_size, void* d_ws, size_t ws_size,
                              hipStream_t stream) {
    const float* x     = (const float*)d_in[0];
    const float* off_w = (const float*)d_in[1];
    const float* off_b = (const float*)d_in[2];
    const float* dw    = (const float*)d_in[3];
    const float* db    = (const float*)d_in[4];

    float* ws   = (float*)d_ws;
    float* p0    = ws;                                       // NPOS*CH f32
    float* p1    = p0 + (size_t)NPOS * CH;                   // NPOS*CH f32
    float* off_g = p1 + (size_t)NPOS * CH;                   // NPOS*18 f32
    unsigned short* wB  = (unsigned short*)(off_g + (size_t)NPOS * 18);  // WB_TOT
    unsigned short* owB = wB + WB_TOT;                       // OWB_TOT
    unsigned short* xT  = owB + OWB_TOT;                     // NPOS*CH bf16

    prep_kernel<<<(WB_TOT + OWB_TOT + 255) / 256, 256, 0, stream>>>(dw, off_w, wB, owB);
    transpose_kernel<<<BN * 576, 256, 0, stream>>>(x, xT);

    for (int l = 0; l < NL; ++l) {
        off_mfma_kernel<<<NBLK, 256, 0, stream>>>(
            xT, owB + (size_t)l * OWB_PER_L, off_b + l * 18, off_g);
        deform_mfma_kernel<<<NBLK * 2, 256, 0, stream>>>(
            xT, off_g, wB + (size_t)l * WB_PER_L, p0, p1);
        if (l < NL - 1)
            sum_cl_kernel<<<(NPOS * CH / 4) / 256, 256, 0, stream>>>(p0, p1, db + l * CH, xT);
        else
            sum_nchw_kernel<<<(NPOS / 64) * 4, 256, 0, stream>>>(p0, p1, db + l * CH,
                                                                 (float*)d_out);
    }
}

// Round 9
// 434.657 us; speedup vs baseline: 2.0959x; 1.1350x over previous
//
#include <hip/hip_runtime.h>

#define BN 2
#define CH 256
#define HH 96
#define WW 96
#define NL 4
#define HW (HH*WW)        // 9216
#define KK (CH*9)         // 2304
#define NPOS (BN*HW)      // 18432

#define MPOS 32           // positions per block
#define NBLK (NPOS/MPOS)  // 576 position-blocks
#define CKCH 32           // channels per K-chunk
#define CKLEN (CKCH*9)    // 288 cols per chunk
#define NCKS 4            // chunks per split (split = 128 channels)
#define SAMW2 296         // ushort row stride: 592 B

#define WB_PER_L (288*256*8)    // main weights bf16/layer
#define WB_TOT (NL*WB_PER_L)
#define OWB_PER_L (288*32*8)    // off weights bf16/layer (N padded to 32)
#define OWB_TOT (NL*OWB_PER_L)

typedef __attribute__((ext_vector_type(8))) short short8;
typedef __attribute__((ext_vector_type(4))) float f32x4;

__device__ __forceinline__ unsigned short f2bf(float f) {
    union { float f; unsigned int u; } v; v.f = f;
    unsigned int r = v.u + 0x7fffu + ((v.u >> 16) & 1u);
    return (unsigned short)(r >> 16);
}

// Pack dw -> wB and off_w -> owB (both bf16 B-frag order over permuted cols).
// Permuted column: col = ck*288 + t9*32 + ci, channel c = ck*32 + ci.
__global__ void prep_kernel(const float* __restrict__ dw, const float* __restrict__ off_w,
                            unsigned short* __restrict__ wB, unsigned short* __restrict__ owB) {
    int idx = blockIdx.x * 256 + threadIdx.x;
    if (idx < WB_TOT) {
        int j  = idx & 7;
        int oc = (idx >> 3) & 255;
        int g  = (idx >> 11) % 288;
        int l  = idx / WB_PER_L;
        int col = g * 8 + j;
        int ck = col / CKLEN;
        int r  = col - ck * CKLEN;
        int t9 = r >> 5;
        int ci = r & 31;
        int c  = ck * CKCH + ci;
        wB[idx] = f2bf(dw[((size_t)(l * CH + oc) * CH + c) * 9 + t9]);
    } else {
        int i2 = idx - WB_TOT;
        if (i2 >= OWB_TOT) return;
        int j   = i2 & 7;
        int ocp = (i2 >> 3) & 31;
        int g   = (i2 >> 8) % 288;
        int l   = i2 / OWB_PER_L;
        int col = g * 8 + j;
        int ck = col / CKLEN;
        int r  = col - ck * CKLEN;
        int t9 = r >> 5;
        int ci = r & 31;
        int c  = ck * CKCH + ci;
        owB[i2] = (ocp < 18) ? f2bf(off_w[((size_t)(l * 18 + ocp) * CH + c) * 9 + t9]) : 0;
    }
}

// Layer-0 only: NCHW f32 -> channel-last bf16 xT[b][hw][c].
__global__ void __launch_bounds__(256)
transpose_kernel(const float* __restrict__ src, unsigned short* __restrict__ xT) {
    __shared__ float tile[64][65];
    int blk = blockIdx.x;
    int b = blk / 576, r = blk - 576 * b;
    int hw0 = (r >> 2) * 64, c0 = (r & 3) * 64;
    int tid = threadIdx.x;
    int lane = tid & 63, grp = tid >> 6;
    const float* sp = src + (size_t)(b * CH + c0) * HW + hw0;
    #pragma unroll
    for (int i = 0; i < 16; ++i) {
        int c = grp * 16 + i;
        tile[c][lane] = sp[(size_t)c * HW + lane];
    }
    __syncthreads();
    unsigned short* dp = xT + (size_t)(b * HW + hw0) * CH + c0;
    #pragma unroll
    for (int i = 0; i < 16; ++i) {
        int hw = grp * 16 + i;
        dp[(size_t)hw * CH + lane] = f2bf(tile[lane][hw]);
    }
}

// Offset conv as MFMA with DIRECT global A-fragment loads (no LDS staging).
// k-tile kb == tap t9 under the permuted col order; A-frag for lane (m,q) is
// 16 contiguous bytes at xT[shifted pos][ck*32 + q*8]. Invalid taps -> zero frag.
__global__ void __launch_bounds__(256)
off_mfma_kernel(const unsigned short* __restrict__ xT, const unsigned short* __restrict__ owB,
                const float* __restrict__ ob, float* __restrict__ off_g) {
    __shared__ int rtab[MPOS * 9];
    const int tid = threadIdx.x;
    int pb = (int)blockIdx.x;
    pb = (pb & 7) * (NBLK / 8) + (pb >> 3);      // XCD swizzle
    const int pos0 = pb * MPOS;
    const int b0   = pos0 / HW;
    const int rem0 = pos0 - b0 * HW;
    const int h0   = rem0 / WW;
    const int w0   = rem0 - h0 * WW;

    for (int rec = tid; rec < MPOS * 9; rec += 256) {
        int p = rec / 9, t9 = rec - 9 * p;
        int dy = t9 / 3 - 1, dx = t9 - 3 * (t9 / 3) - 1;
        int y = h0 + dy, xw = w0 + p + dx;
        bool valid = ((unsigned)y < HH) && ((unsigned)xw < WW);
        rtab[rec] = valid ? (y * WW + xw) * CH : -1;
    }
    __syncthreads();

    const int m   = tid & 15;
    const int q   = (tid >> 4) & 3;
    const int wvi = tid >> 6;
    const int mt  = wvi & 1;          // position-tile
    const int nt  = wvi >> 1;         // oc-tile
    const int p   = mt * 16 + m;      // this lane's A row = position

    const unsigned short* xq = xT + (size_t)b0 * HW * CH + q * 8;
    const unsigned short* wq = owB + (size_t)(nt * 16 + m) * 8;

    f32x4 acc0 = {}, acc1 = {};
    for (int kb = 0; kb < 9; ++kb) {
        int s0 = rtab[p * 9 + kb];
        const unsigned short* ap = xq + s0;
        #pragma unroll
        for (int ck = 0; ck < 8; ++ck) {
            short8 av = {};
            if (s0 >= 0) av = *(const short8*)(ap + ck * CKCH);
            short8 bv = *(const short8*)(wq + (size_t)(ck * 36 + kb * 4 + q) * (32 * 8));
            if (ck & 1) acc1 = __builtin_amdgcn_mfma_f32_16x16x32_bf16(av, bv, acc1, 0, 0, 0);
            else        acc0 = __builtin_amdgcn_mfma_f32_16x16x32_bf16(av, bv, acc0, 0, 0, 0);
        }
    }
    // D: row(pos) = q*4+r, col(oc) = m
    int oc = nt * 16 + m;
    if (oc < 18) {
        float bsv = ob[oc];
        #pragma unroll
        for (int r = 0; r < 4; ++r) {
            int pp = mt * 16 + q * 4 + r;
            off_g[(size_t)(pos0 + pp) * 18 + oc] = acc0[r] + acc1[r] + bsv;
        }
    }
}

// Split-K fused sampling + MFMA. bid = pos-block*2 + split.
// Writes channel-last f32 partials pCL[pos][256].
__global__ void __launch_bounds__(256, 5)
deform_mfma_kernel(const unsigned short* __restrict__ xT, const float* __restrict__ off_g,
                   const unsigned short* __restrict__ wB,
                   float* __restrict__ dst0, float* __restrict__ dst1) {
    __shared__ __align__(16) unsigned short sam[MPOS * SAMW2];  // 18944 B, reused as cT
    __shared__ float offs[MPOS * 18];                           // 2304 B
    __shared__ __align__(16) uint4 taps4[MPOS * 9];             // 4608 B
    __shared__ unsigned short dso16[MPOS * 9];                  // 576 B
    const int tid = threadIdx.x;
    const int s   = (int)blockIdx.x & 1;
    int pb = (int)blockIdx.x >> 1;
    pb = (pb & 7) * (NBLK / 8) + (pb >> 3);      // XCD swizzle
    const int pos0 = pb * MPOS;
    const int b0   = pos0 / HW;
    const int rem0 = pos0 - b0 * HW;
    const int h0   = rem0 / WW;
    const int w0   = rem0 - h0 * WW;

    for (int i = tid; i < MPOS * 18; i += 256)
        offs[i] = off_g[(size_t)pos0 * 18 + i];
    __syncthreads();

    // ---- tap table: 288 records, packed to one uint4 + ushort dso ----
    for (int rec = tid; rec < MPOS * 9; rec += 256) {
        int p  = rec / 9, t9 = rec - 9 * p;
        int ky = t9 / 3, kx = t9 - 3 * (t9 / 3);
        float py = (float)(h0 - 1 + ky) + offs[p * 18 + 2 * t9];
        float px = (float)(w0 + p - 1 + kx) + offs[p * 18 + 2 * t9 + 1];
        float yf = floorf(py), xf = floorf(px);
        int y0 = (int)yf, x0 = (int)xf;
        float wy1 = py - yf, wx1 = px - xf;
        float fy0 = ((unsigned)y0       < HH) ? 1.f - wy1 : 0.f;
        float fy1 = ((unsigned)(y0 + 1) < HH) ? wy1       : 0.f;
        float fx0 = ((unsigned)x0       < WW) ? 1.f - wx1 : 0.f;
        float fx1 = ((unsigned)(x0 + 1) < WW) ? wx1       : 0.f;
        int y0c = min(max(y0, 0), HH - 1), y1c = min(max(y0 + 1, 0), HH - 1);
        int x0c = min(max(x0, 0), WW - 1), x1c = min(max(x0 + 1, 0), WW - 1);
        int bx  = min(max(x0, 0), WW - 2);
        float wA  = (x0c == bx     ? fx0 : 0.f) + (x1c == bx     ? fx1 : 0.f);
        float wBv = (x0c == bx + 1 ? fx0 : 0.f) + (x1c == bx + 1 ? fx1 : 0.f);
        uint4 tv;
        tv.x = (unsigned int)((y0c * WW + bx) * CH);
        tv.y = (unsigned int)((y1c * WW + bx) * CH);
        tv.z = (unsigned int)f2bf(fy0 * wA) | ((unsigned int)f2bf(fy0 * wBv) << 16);
        tv.w = (unsigned int)f2bf(fy1 * wA) | ((unsigned int)f2bf(fy1 * wBv) << 16);
        taps4[rec] = tv;
        dso16[rec] = (unsigned short)(p * SAMW2 + t9 * 32);
    }

    const int lane = tid & 63;
    const int wvi  = tid >> 6;
    const int cp   = lane & 15;      // channel pair within chunk
    const int rsub = lane >> 4;      // record sub-slot
    const int m    = tid & 15;
    const int q    = (tid >> 4) & 3;

    f32x4 acc[2][4] = {};
    const unsigned short* xTb = xT + (size_t)b0 * HW * CH;

    for (int ckl = 0; ckl < NCKS; ++ckl) {
        const int ck = s * NCKS + ckl;
        __syncthreads();
        const unsigned short* xs = xTb + ck * CKCH + cp * 2;
        #pragma unroll 3
        for (int rr = 0; rr < 18; ++rr) {
            int rec = wvi * 72 + rr * 4 + rsub;
            uint4 tv = taps4[rec];
            int dso  = dso16[rec];
            float u0 = __uint_as_float(tv.z << 16);
            float u1 = __uint_as_float(tv.z & 0xFFFF0000u);
            float u2 = __uint_as_float(tv.w << 16);
            float u3 = __uint_as_float(tv.w & 0xFFFF0000u);
            unsigned int A0, A1, C0, C1;
            __builtin_memcpy(&A0, xs + tv.x, 4);
            __builtin_memcpy(&A1, xs + tv.x + CH, 4);
            __builtin_memcpy(&C0, xs + tv.y, 4);
            __builtin_memcpy(&C1, xs + tv.y + CH, 4);
            // element-wise float2 chains -> v_pk_fma_f32 (bit-identical math)
            float2 a0 = make_float2(__uint_as_float(A0 << 16), __uint_as_float(A0 & 0xFFFF0000u));
            float2 a1 = make_float2(__uint_as_float(A1 << 16), __uint_as_float(A1 & 0xFFFF0000u));
            float2 c0 = make_float2(__uint_as_float(C0 << 16), __uint_as_float(C0 & 0xFFFF0000u));
            float2 c1 = make_float2(__uint_as_float(C1 << 16), __uint_as_float(C1 & 0xFFFF0000u));
            float2 vv;
            vv.x = a0.x * u0;               vv.y = a0.y * u0;
            vv.x = fmaf(a1.x, u1, vv.x);    vv.y = fmaf(a1.y, u1, vv.y);
            vv.x = fmaf(c0.x, u2, vv.x);    vv.y = fmaf(c0.y, u2, vv.y);
            vv.x = fmaf(c1.x, u3, vv.x);    vv.y = fmaf(c1.y, u3, vv.y);
            unsigned int packed = (unsigned int)f2bf(vv.x) | ((unsigned int)f2bf(vv.y) << 16);
            *(unsigned int*)(sam + dso + cp * 2) = packed;
        }
        __syncthreads();
        const unsigned short* arow0 = sam + m * SAMW2 + q * 8;
        const unsigned short* arow1 = arow0 + 16 * SAMW2;
        const int g0 = ck * 36;
        for (int kb = 0; kb < 9; ++kb) {
            short8 av0 = *(const short8*)(arow0 + kb * 32);
            short8 av1 = *(const short8*)(arow1 + kb * 32);
            const unsigned short* wkb = wB + ((size_t)(g0 + kb * 4 + q) * 256
                                             + (wvi * 64 + m)) * 8;
            #pragma unroll
            for (int t = 0; t < 4; ++t) {
                short8 bv = *(const short8*)(wkb + t * 16 * 8);
                acc[0][t] = __builtin_amdgcn_mfma_f32_16x16x32_bf16(av0, bv, acc[0][t], 0, 0, 0);
                acc[1][t] = __builtin_amdgcn_mfma_f32_16x16x32_bf16(av1, bv, acc[1][t], 0, 0, 0);
            }
        }
    }

    // ---- epilogue: channel-last partials pCL[pos][256] ----
    float* dst = s ? dst1 : dst0;
    float* cT = (float*)sam;                 // [256][17] f32 = 17408 B
    #pragma unroll
    for (int mt = 0; mt < 2; ++mt) {
        __syncthreads();
        #pragma unroll
        for (int t = 0; t < 4; ++t) {
            int oc = wvi * 64 + t * 16 + m;
            #pragma unroll
            for (int r = 0; r < 4; ++r)
                cT[oc * 17 + q * 4 + r] = acc[mt][t][r];
        }
        __syncthreads();
        float* dp = dst + (size_t)(pos0 + mt * 16) * CH + tid;
        #pragma unroll 4
        for (int p = 0; p < 16; ++p)
            dp[(size_t)p * CH] = cT[tid * 17 + p];
    }
}

// Layers 0-2 epilogue: xT = bf16(relu(p0 + p1 + bias)), channel-last (elementwise).
__global__ void __launch_bounds__(256)
sum_cl_kernel(const float* __restrict__ p0, const float* __restrict__ p1,
              const float* __restrict__ db, unsigned short* __restrict__ xT) {
    unsigned int idx = blockIdx.x * 256 + threadIdx.x;   // 4-elem group
    unsigned int e = idx * 4;
    unsigned int oc = e & (CH - 1);
    float4 bsv = *(const float4*)(db + oc);
    float4 a = *(const float4*)(p0 + e);
    float4 b = *(const float4*)(p1 + e);
    unsigned short o[4];
    o[0] = f2bf(fmaxf(a.x + b.x + bsv.x, 0.f));
    o[1] = f2bf(fmaxf(a.y + b.y + bsv.y, 0.f));
    o[2] = f2bf(fmaxf(a.z + b.z + bsv.z, 0.f));
    o[3] = f2bf(fmaxf(a.w + b.w + bsv.w, 0.f));
    __builtin_memcpy(xT + e, o, 8);
}

// Final layer epilogue: d_out(NCHW f32) = relu(p0 + p1 + bias), LDS transpose.
__global__ void __launch_bounds__(256)
sum_nchw_kernel(const float* __restrict__ p0, const float* __restrict__ p1,
                const float* __restrict__ db, float* __restrict__ out) {
    __shared__ float tile[64][65];
    int blk = blockIdx.x;
    int hw0 = (blk >> 2) * 64;            // flat pos base (never crosses batch)
    int oc0 = (blk & 3) * 64;
    int tid = threadIdx.x;
    int lane = tid & 63, grp = tid >> 6;
    float bsv = db[oc0 + lane];
    #pragma unroll
    for (int i = 0; i < 16; ++i) {
        int r = grp * 16 + i;
        size_t e = (size_t)(hw0 + r) * CH + oc0 + lane;
        tile[r][lane] = fmaxf(p0[e] + p1[e] + bsv, 0.f);
    }
    __syncthreads();
    int b = hw0 / HW, hwl = hw0 - b * HW;
    #pragma unroll
    for (int i = 0; i < 16; ++i) {
        int oc = grp * 16 + i;
        out[((size_t)(b * CH) + oc0 + oc) * HW + hwl + lane] = tile[lane][oc];
    }
}

extern "C" void kernel_launch(void* const* d_in, const int* in_sizes, int n_in,
                              void* d_out, int out_size, void* d_ws, size_t ws_size,
                              hipStream_t stream) {
    const float* x     = (const float*)d_in[0];
    const float* off_w = (const float*)d_in[1];
    const float* off_b = (const float*)d_in[2];
    const float* dw    = (const float*)d_in[3];
    const float* db    = (const float*)d_in[4];

    float* ws   = (float*)d_ws;
    float* p0    = ws;                                       // NPOS*CH f32
    float* p1    = p0 + (size_t)NPOS * CH;                   // NPOS*CH f32
    float* off_g = p1 + (size_t)NPOS * CH;                   // NPOS*18 f32
    unsigned short* wB  = (unsigned short*)(off_g + (size_t)NPOS * 18);  // WB_TOT
    unsigned short* owB = wB + WB_TOT;                       // OWB_TOT
    unsigned short* xT  = owB + OWB_TOT;                     // NPOS*CH bf16

    prep_kernel<<<(WB_TOT + OWB_TOT + 255) / 256, 256, 0, stream>>>(dw, off_w, wB, owB);
    transpose_kernel<<<BN * 576, 256, 0, stream>>>(x, xT);

    for (int l = 0; l < NL; ++l) {
        off_mfma_kernel<<<NBLK, 256, 0, stream>>>(
            xT, owB + (size_t)l * OWB_PER_L, off_b + l * 18, off_g);
        deform_mfma_kernel<<<NBLK * 2, 256, 0, stream>>>(
            xT, off_g, wB + (size_t)l * WB_PER_L, p0, p1);
        if (l < NL - 1)
            sum_cl_kernel<<<(NPOS * CH / 4) / 256, 256, 0, stream>>>(p0, p1, db + l * CH, xT);
        else
            sum_nchw_kernel<<<(NPOS / 64) * 4, 256, 0, stream>>>(p0, p1, db + l * CH,
                                                                 (float*)d_out);
    }
}